// Round 13
// baseline (171.698 us; speedup 1.0000x reference)
//
#include <hip/hip_runtime.h>
#include <hip/hip_bf16.h>
#include <math.h>

#define HH 64
#define WW 64
#define HW 4096
#define LDV 136  // V row stride in bf16 elems (272 B: 16B-aligned, stride%32words=4 -> 2-way banks, free)

typedef __bf16 bf16x8 __attribute__((ext_vector_type(8)));
typedef float floatx4 __attribute__((ext_vector_type(4)));
typedef unsigned int uint4a __attribute__((ext_vector_type(4)));
typedef unsigned int uint2a __attribute__((ext_vector_type(2)));

// ws layout (byte offsets)
#define WS_Y    0u          // float y[8][128][4096]   16777216 B
#define WS_PSQ  16777216u   // float[256]  (sum, sumsq per channel)
#define WS_XTB  16778240u   // bf16 xtb[8][4096][128]   8388608 B
#define WS_WTB  25166848u   // bf16 wtb[9][128][128]     294912 B
#define WS_OWB  25461760u   // bf16 owb[9][32][128]       73728 B

static __device__ inline ushort f2bf(float f) {
  __hip_bfloat16 h = __float2bfloat16(f);
  return __builtin_bit_cast(ushort, h);
}
static __device__ inline float lo16(unsigned int u) { return __builtin_bit_cast(float, u << 16); }
static __device__ inline float hi16(unsigned int u) { return __builtin_bit_cast(float, u & 0xffff0000u); }

// ---------------- fused prep: x transpose + weight converts + psq zero ------
__global__ __launch_bounds__(256) void k_prep(const float* __restrict__ x,
                                              const float* __restrict__ w,
                                              const float* __restrict__ ow,
                                              ushort* __restrict__ xtb,
                                              ushort* __restrict__ wtb,
                                              ushort* __restrict__ owb,
                                              float* __restrict__ psq) {
  __shared__ float tile[32][33];
  int bid = blockIdx.x;
  if (bid < 4096) {
    int hw0 = (bid & 127) * 32;
    int c0 = ((bid >> 7) & 3) * 32;
    int b = bid >> 9;
    int col = threadIdx.x & 31, row = threadIdx.x >> 5;
    const float* xb = x + ((size_t)b * 128 + c0) * HW + hw0;
#pragma unroll
    for (int i = 0; i < 32; i += 8)
      tile[row + i][col] = xb[(size_t)(row + i) * HW + col];
    __syncthreads();
    int hw = threadIdx.x >> 3, cq = threadIdx.x & 7;
    ushort* xo = xtb + ((size_t)b * HW + hw0) * 128 + c0;
    unsigned int lo = (unsigned int)f2bf(tile[cq * 4 + 0][hw]) |
                      ((unsigned int)f2bf(tile[cq * 4 + 1][hw]) << 16);
    unsigned int hi = (unsigned int)f2bf(tile[cq * 4 + 2][hw]) |
                      ((unsigned int)f2bf(tile[cq * 4 + 3][hw]) << 16);
    uint2a v2 = (uint2a){lo, hi};
    *(uint2a*)(&xo[(size_t)hw * 128 + cq * 4]) = v2;
  } else if (bid < 4096 + 576) {
    int idx = (bid - 4096) * 256 + threadIdx.x;  // < 147456
    int c = idx & 127, o = (idx >> 7) & 127, k = idx >> 14;
    wtb[idx] = f2bf(w[(o * 128 + c) * 9 + k]);
  } else if (bid < 4096 + 720) {
    int j = (bid - 4672) * 256 + threadIdx.x;  // < 36864
    int c = j & 127, o = (j >> 7) & 31, k = j >> 12;
    float v = (o < 27) ? ow[(o * 128 + c) * 9 + k] : 0.f;
    owb[j] = f2bf(v);
  } else {
    psq[threadIdx.x] = 0.f;
  }
}

// ---------------- fused offset-conv + deformable GEMM + BN partials ---------
// grid (128 half-rows, 8 batch), 256 threads = 4 waves. Tile: 128 o x 32 p.
// BULK-STAGED: all 9 taps' V staged to LDS in one barrier-free burst (72
// gathers deep MLP, nothing drains the queue), then ONE long MFMA run.
// Barriers/block: 4 (was 18). LDS 81.8 KB -> 2 blocks/CU.
__global__ __launch_bounds__(256, 2) void k_main(
    const ushort* __restrict__ xtb, const ushort* __restrict__ wtb,
    const ushort* __restrict__ owb, const float* __restrict__ off_b,
    const float* __restrict__ bias, float* __restrict__ y,
    float* __restrict__ psq) {
  __shared__ ushort Vk[9][32 * LDV];  // 78336 B
  __shared__ float omL[27 * 32];      // 3456 B; aliased by sps/sqs in epilogue
  int t = threadIdx.x;
  int lane = t & 63, wv = t >> 6;
  int li = lane & 15, quad = lane >> 4;
  int hr = blockIdx.x;
  int row = hr >> 1, p0b = (hr & 1) * 32;
  int b = blockIdx.y;
  const ushort* xb = xtb + (size_t)b * HW * 128;
  int ch = t & 15;   // 16-B chunk within the 256-B pixel row
  int pq = t >> 4;   // staging pixel (0..15); passes: pq and pq+16

  // ===== phase 1a: bulk-stage undeformed taps (no barriers) =====
#pragma unroll
  for (int k = 0; k < 9; ++k) {
    int ky = k / 3, kx = k % 3;
    int ry = row - 1 + ky;
#pragma unroll
    for (int pp = 0; pp < 2; ++pp) {
      int p = pq + pp * 16;
      int cx = p0b + p - 1 + kx;
      bool v = (ry >= 0 && ry < HH && cx >= 0 && cx < WW);
      int idx = v ? (ry * WW + cx) : 0;
      uint4a a = *(const uint4a*)(xb + (size_t)idx * 128 + ch * 8);
      uint4a d = v ? a : (uint4a){0u, 0u, 0u, 0u};
      *(uint4a*)(&Vk[k][p * LDV + ch * 8]) = d;
    }
  }
  __syncthreads();

  // ===== phase 1b: offset conv MFMA run (no barriers) =====
  int mi = wv & 1, ni = wv >> 1;
  floatx4 oacc = (floatx4){0.f, 0.f, 0.f, 0.f};
  for (int k = 0; k < 9; ++k) {
#pragma unroll
    for (int ks = 0; ks < 4; ++ks) {
      bf16x8 bfrag = __builtin_bit_cast(bf16x8,
          *(const uint4a*)(&Vk[k][(ni * 16 + li) * LDV + ks * 32 + quad * 8]));
      bf16x8 afrag = __builtin_bit_cast(bf16x8,
          *(const uint4a*)(&owb[(size_t)(k * 32 + mi * 16 + li) * 128 + ks * 32 + quad * 8]));
      oacc = __builtin_amdgcn_mfma_f32_16x16x32_bf16(afrag, bfrag, oacc, 0, 0, 0);
    }
  }
#pragma unroll
  for (int r = 0; r < 4; ++r) {
    int o = mi * 16 + quad * 4 + r;
    if (o < 27) omL[o * 32 + ni * 16 + li] = oacc[r] + off_b[o];
  }
  __syncthreads();  // omL visible; all phase-1 Vk reads done

  // ===== phase 2a: bulk-stage deformed taps (no barriers) =====
#pragma unroll 3
  for (int k = 0; k < 9; ++k) {
    int ky = k / 3, kx = k % 3;
#pragma unroll
    for (int pp = 0; pp < 2; ++pp) {
      int p = pq + pp * 16;
      float offy = omL[(2 * k) * 32 + p];
      float offx = omL[(2 * k + 1) * 32 + p];
      float mraw = omL[(18 + k) * 32 + p];
      float m = 1.f / (1.f + __expf(-mraw));
      float py = offy + (float)(row - 1 + ky);
      float px = offx + (float)(p0b + p - 1 + kx);
      float y0f = floorf(py), x0f = floorf(px);
      float ly = py - y0f, lx = px - x0f;
      int iy0 = (int)y0f, ix0 = (int)x0f;
      int iy1 = iy0 + 1, ix1 = ix0 + 1;
      float w00 = (1.f - ly) * (1.f - lx) * m, w01 = (1.f - ly) * lx * m;
      float w10 = ly * (1.f - lx) * m, w11 = ly * lx * m;
      if (iy0 < 0 || iy0 > HH - 1) { w00 = 0.f; w01 = 0.f; }
      if (iy1 < 0 || iy1 > HH - 1) { w10 = 0.f; w11 = 0.f; }
      if (ix0 < 0 || ix0 > WW - 1) { w00 = 0.f; w10 = 0.f; }
      if (ix1 < 0 || ix1 > WW - 1) { w01 = 0.f; w11 = 0.f; }
      int cy0 = min(max(iy0, 0), HH - 1), cy1 = min(max(iy1, 0), HH - 1);
      int cx0 = min(max(ix0, 0), WW - 1), cx1 = min(max(ix1, 0), WW - 1);
      const ushort* base = xb + ch * 8;
      uint4a u0 = *(const uint4a*)(base + (size_t)(cy0 * WW + cx0) * 128);
      uint4a u1 = *(const uint4a*)(base + (size_t)(cy0 * WW + cx1) * 128);
      uint4a u2 = *(const uint4a*)(base + (size_t)(cy1 * WW + cx0) * 128);
      uint4a u3 = *(const uint4a*)(base + (size_t)(cy1 * WW + cx1) * 128);
      uint4a outv;
#pragma unroll
      for (int e = 0; e < 4; ++e) {
        float rlo = w00 * lo16(u0[e]) + w01 * lo16(u1[e]) +
                    w10 * lo16(u2[e]) + w11 * lo16(u3[e]);
        float rhi = w00 * hi16(u0[e]) + w01 * hi16(u1[e]) +
                    w10 * hi16(u2[e]) + w11 * hi16(u3[e]);
        outv[e] = (unsigned int)f2bf(rlo) | ((unsigned int)f2bf(rhi) << 16);
      }
      *(uint4a*)(&Vk[k][p * LDV + ch * 8]) = outv;
    }
  }
  __syncthreads();

  // ===== phase 2b: main GEMM, one long MFMA run (no barriers) =====
  floatx4 macc[2][2];
#pragma unroll
  for (int i = 0; i < 2; ++i)
#pragma unroll
    for (int j = 0; j < 2; ++j) macc[i][j] = (floatx4){0.f, 0.f, 0.f, 0.f};
  for (int k = 0; k < 9; ++k) {
    const ushort* Arow = &wtb[(size_t)(k * 128 + wv * 32) * 128];
#pragma unroll
    for (int ks = 0; ks < 4; ++ks) {
      bf16x8 b0 = __builtin_bit_cast(bf16x8,
          *(const uint4a*)(&Vk[k][(li)*LDV + ks * 32 + quad * 8]));
      bf16x8 b1 = __builtin_bit_cast(bf16x8,
          *(const uint4a*)(&Vk[k][(16 + li) * LDV + ks * 32 + quad * 8]));
      bf16x8 a0 = __builtin_bit_cast(bf16x8,
          *(const uint4a*)(Arow + (size_t)(li)*128 + ks * 32 + quad * 8));
      bf16x8 a1 = __builtin_bit_cast(bf16x8,
          *(const uint4a*)(Arow + (size_t)(16 + li) * 128 + ks * 32 + quad * 8));
      macc[0][0] = __builtin_amdgcn_mfma_f32_16x16x32_bf16(a0, b0, macc[0][0], 0, 0, 0);
      macc[0][1] = __builtin_amdgcn_mfma_f32_16x16x32_bf16(a0, b1, macc[0][1], 0, 0, 0);
      macc[1][0] = __builtin_amdgcn_mfma_f32_16x16x32_bf16(a1, b0, macc[1][0], 0, 0, 0);
      macc[1][1] = __builtin_amdgcn_mfma_f32_16x16x32_bf16(a1, b1, macc[1][1], 0, 0, 0);
    }
  }

  // ===== epilogue: bias + y store + fused BN partials =====
  float* sps = omL;        // alias: omL dead after phase-2a
  float* sqs = omL + 128;
#pragma unroll
  for (int ot = 0; ot < 2; ++ot)
#pragma unroll
    for (int r = 0; r < 4; ++r) {
      int o = wv * 32 + ot * 16 + quad * 4 + r;
      float bb = bias[o];
      float s = 0.f, q = 0.f;
#pragma unroll
      for (int pt = 0; pt < 2; ++pt) {
        int p = p0b + pt * 16 + li;
        float val = macc[ot][pt][r] + bb;
        y[((size_t)(b * 128 + o)) * HW + row * 64 + p] = val;
        s += val;
        q += val * val;
      }
#pragma unroll
      for (int off = 8; off >= 1; off >>= 1) {
        s += __shfl_down(s, off, 16);
        q += __shfl_down(q, off, 16);
      }
      if (li == 0) {  // unique o per (wv,ot,quad,r): no collisions
        sps[o] = s;
        sqs[o] = q;
      }
    }
  __syncthreads();
  if (t < 128) atomicAdd(&psq[t], sps[t]);
  else atomicAdd(&psq[t], sqs[t - 128]);
}

// ---------------- normalize + ReLU (scale/shift computed inline) ------------
__global__ __launch_bounds__(256) void k_norm(const float* __restrict__ y,
                                              const float* __restrict__ psq,
                                              const float* __restrict__ gamma,
                                              const float* __restrict__ beta,
                                              float* __restrict__ out) {
  int blk = blockIdx.x;
  int o = (blk >> 2) & 127;
  float s = psq[o], q = psq[128 + o];
  float mean = s * (1.f / 32768.f);
  float var = q * (1.f / 32768.f) - mean * mean;
  float scale = gamma[o] * rsqrtf(var + 1e-5f);
  float shift = beta[o] - mean * scale;
  int i4 = blk * 256 + threadIdx.x;
  float4 v = ((const float4*)y)[i4];
  float4 r;
  r.x = fmaxf(v.x * scale + shift, 0.f);
  r.y = fmaxf(v.y * scale + shift, 0.f);
  r.z = fmaxf(v.z * scale + shift, 0.f);
  r.w = fmaxf(v.w * scale + shift, 0.f);
  ((float4*)out)[i4] = r;
}

extern "C" void kernel_launch(void* const* d_in, const int* in_sizes, int n_in,
                              void* d_out, int out_size, void* d_ws, size_t ws_size,
                              hipStream_t stream) {
  const float* x     = (const float*)d_in[0];
  const float* off_w = (const float*)d_in[1];
  const float* off_b = (const float*)d_in[2];
  const float* w     = (const float*)d_in[3];
  const float* bias  = (const float*)d_in[4];
  const float* gamma = (const float*)d_in[5];
  const float* beta  = (const float*)d_in[6];
  float* out = (float*)d_out;
  char* ws = (char*)d_ws;

  float* y    = (float*)(ws + WS_Y);
  float* psq  = (float*)(ws + WS_PSQ);
  ushort* xtb = (ushort*)(ws + WS_XTB);
  ushort* wtb = (ushort*)(ws + WS_WTB);
  ushort* owb = (ushort*)(ws + WS_OWB);

  k_prep<<<4817, 256, 0, stream>>>(x, w, off_w, xtb, wtb, owb, psq);
  k_main<<<dim3(128, 8), 256, 0, stream>>>(xtb, wtb, owb, off_b, bias, y, psq);
  k_norm<<<4096, 256, 0, stream>>>(y, psq, gamma, beta, out);
}